// Round 10
// baseline (327.830 us; speedup 1.0000x reference)
//
#include <hip/hip_runtime.h>

#define BB 2
#define HH 16
#define SS 2048
#define DD 64
#define QT 64
#define KT 64
#define NKT (SS / KT)
#define LP 72           // Ps padded row stride (halfs)
#define TILE_BYTES 8192 // one 64x64 fp16/bf16 tile
#define WS_KHI 0
#define WS_KLO (32u * 32u * 8192u)
#define WS_VT  (2u * 32u * 32u * 8192u)
#define WS_MASK ((size_t)3 * 32 * 32 * 8192)
#define WS_KV_NEED ((size_t)3 * 32 * 32 * 8192)
#define WS_FULL_NEED (WS_KV_NEED + ((size_t)1 << 24))  // +16.78 MB mask
#define QSCALE 0.18033688f  // 0.125 * log2(e): softmax in exp2 domain

using bf16x8 = __attribute__((ext_vector_type(8))) short;
using half8  = __attribute__((ext_vector_type(8))) _Float16;
using f32x4  = __attribute__((ext_vector_type(4))) float;
using fp16x2 = __attribute__((ext_vector_type(2))) __fp16;  // cvt_pkrtz return type

typedef __attribute__((address_space(3))) unsigned lds_u32;
typedef __attribute__((address_space(1))) unsigned gvm_u32;
#define GLOAD16(gp, lp) \
  __builtin_amdgcn_global_load_lds((gvm_u32*)(gp), (lds_u32*)(lp), 16, 0, 0)

// JAX threefry2x32, key (0,42), partitionable: input (0, i), bits = out0^out1.
// keep ⟺ bits < 0xE6666600 (exact reformulation of u<0.9f). Verified r2-r8.
__device__ __forceinline__ unsigned tf_bits(unsigned i) {
  const unsigned ks1 = 42u;
  const unsigned ks2 = 0x1BD11BDAu ^ 42u;
  unsigned x0 = 0u;
  unsigned x1 = i + ks1;
#define TF_R(r) { x0 += x1; x1 = __builtin_rotateleft32(x1, r) ^ x0; }
  TF_R(13) TF_R(15) TF_R(26) TF_R(6)
  x0 += ks1; x1 += ks2 + 1u;
  TF_R(17) TF_R(29) TF_R(16) TF_R(24)
  x0 += ks2; x1 += 2u;
  TF_R(13) TF_R(15) TF_R(26) TF_R(6)
  x1 += ks1 + 3u;
  TF_R(17) TF_R(29) TF_R(16) TF_R(24)
  x0 += ks1; x1 += ks2 + 4u;
  TF_R(13) TF_R(15) TF_R(26) TF_R(6)
  x0 += ks2; x1 += 5u;
#undef TF_R
  return x0 ^ x1;
}

// ---- fused prep: blocks [0,2048) K-split, [2048,4096) V-transpose,
// [4096,36864) dropout-mask threefry (VALU-bound, co-resident with the
// memory-bound K/V blocks on other CUs). Mask stored as u16 per
// (bh,qt,kt,w,lane) in EXACT main-kernel consumption order.
__global__ __launch_bounds__(256)
void prep_all(const float* __restrict__ Kg, const float* __restrict__ Vg,
              char* __restrict__ ws) {
  if (blockIdx.x < 2048) {
    const int g = blockIdx.x * 256 + threadIdx.x;
    const int ck = g & 7, row = (g >> 3) & 63, kt = (g >> 9) & 31, bh = g >> 14;
    const int b = bh >> 4, h = bh & 15;
    const float* src = Kg + (((size_t)b * SS + kt * 64 + row) * HH + h) * DD + ck * 8;
    float f[8];
    *(float4*)&f[0] = ((const float4*)src)[0];
    *(float4*)&f[4] = ((const float4*)src)[1];
    unsigned short hi[8], lo[8];
    #pragma unroll
    for (int j = 0; j < 8; ++j) {
      unsigned u = __float_as_uint(f[j]);
      hi[j] = (unsigned short)(u >> 16);
      float l = f[j] - __uint_as_float(u & 0xFFFF0000u);
      lo[j] = (unsigned short)(__float_as_uint(l) >> 16);
    }
    const size_t toff = (size_t)(bh * NKT + kt) * TILE_BYTES + row * 128 +
                        ((unsigned)(ck ^ (row & 7))) * 16;
    *(uint4*)(ws + WS_KHI + toff) = *(uint4*)hi;
    *(uint4*)(ws + WS_KLO + toff) = *(uint4*)lo;
  } else if (blockIdx.x < 4096) {
    const int g2 = blockIdx.x * 256 + threadIdx.x - (1 << 19);
    const int d = g2 & 63, ck = (g2 >> 6) & 7, kt = (g2 >> 9) & 31, bh = g2 >> 14;
    const int b = bh >> 4, h = bh & 15;
    const float* src = Vg + (((size_t)b * SS + kt * 64 + ck * 8) * HH + h) * DD + d;
    _Float16 hv[8];
    #pragma unroll
    for (int j = 0; j < 8; ++j)
      hv[j] = (_Float16)src[(size_t)j * HH * DD];
    const size_t toff = (size_t)(bh * NKT + kt) * TILE_BYTES + d * 128 +
                        ((unsigned)(ck ^ (d & 7))) * 16;
    *(uint4*)(ws + WS_VT + toff) = *(uint4*)hv;
  } else {
    // mask: g in [0, 2^23): lane(6) | w(2) | kt(5) | qt(5) | bh(5)
    const unsigned g = (blockIdx.x - 4096) * 256 + threadIdx.x;
    const int lane = g & 63, w = (g >> 6) & 3, kt = (g >> 8) & 31;
    const int qt = (g >> 13) & 31, bh = g >> 18;
    const unsigned qrow = (unsigned)(qt * 64 + w * 16 + (lane & 15));
    const unsigned fb = ((unsigned)bh * SS + qrow) * SS + (unsigned)((lane >> 4) * 4)
                        + (unsigned)(kt * KT);
    unsigned m = 0;
    #pragma unroll
    for (int k4 = 0; k4 < 4; ++k4)
      #pragma unroll
      for (int r = 0; r < 4; ++r)
        m |= (tf_bits(fb + (unsigned)(k4 * 16 + r)) < 0xE6666600u ? 1u : 0u)
             << (k4 * 4 + r);
    const size_t midx = ((((size_t)(bh * 32 + qt) * 32 + kt) * 4 + w) * 64 + lane);
    *(unsigned short*)(ws + WS_MASK + 2 * midx) = (unsigned short)m;
  }
}

// grid (32, 32): one block per (64-q tile, b*H+h). 4 waves; wave w owns
// q-rows [16w,16w+16). SWAPPED QK^T: mfma(K,Q) -> D[k][q]; lane holds a
// full q-row -> in-register softmax (exp2 domain). Mask: WSMASK ? precomputed
// u16 stream : in-situ threefry. Single-buffer LDS 33 KB -> 4 blocks/CU
// (whole grid resident; r6-r8 showed time invariant to staging schedule).
template<bool WSMASK>
__global__ __launch_bounds__(256, 4)
void fused_attn_t(const float* __restrict__ Qg, const char* __restrict__ ws,
                  const unsigned short* __restrict__ maskws,
                  float* __restrict__ Og) {
  __shared__ __attribute__((aligned(16))) unsigned short KsHi[4096];
  __shared__ __attribute__((aligned(16))) unsigned short KsLo[4096];
  __shared__ __attribute__((aligned(16))) _Float16 VtL[4096];
  __shared__ __attribute__((aligned(16))) _Float16 Ps[QT][LP];

  const int t   = threadIdx.x;
  const int w   = t >> 6;
  const int l   = t & 63;
  const int l15 = l & 15;
  const int hi4 = l >> 4;
  const int e8  = l15 & 7;

  const int qtile = blockIdx.x;
  const int qt0 = qtile * QT;
  const int bh  = blockIdx.y;
  const int b   = bh >> 4, h = bh & 15;

  // ---- Q B-fragments in registers (bf16 hi/lo of QSCALE*q, exp2 domain) ----
  bf16x8 qh[2], ql[2];
  {
    const float* qp = Qg + (((size_t)b * SS + qt0 + 16 * w + l15) * HH + h) * DD + hi4 * 8;
    #pragma unroll
    for (int c = 0; c < 2; ++c) {
      float f[8];
      *(float4*)&f[0] = *(const float4*)(qp + c * 32);
      *(float4*)&f[4] = *(const float4*)(qp + c * 32 + 4);
      #pragma unroll
      for (int j = 0; j < 8; ++j) {
        float qs = QSCALE * f[j];
        unsigned u = __float_as_uint(qs);
        qh[c][j] = (short)(u >> 16);
        float lo = qs - __uint_as_float(u & 0xFFFF0000u);
        ql[c][j] = (short)(__float_as_uint(lo) >> 16);
      }
    }
  }

  f32x4 o[4];
  #pragma unroll
  for (int i = 0; i < 4; ++i) o[i] = (f32x4){0.f, 0.f, 0.f, 0.f};
  float mrow = -1e30f, lrow = 0.f;

  unsigned fb = 0;
  const unsigned short* mp = nullptr;
  if constexpr (WSMASK) {
    mp = maskws + (size_t)(bh * 32 + qtile) * 32 * 256 + w * 64 + l;
  } else {
    fb = ((unsigned)bh * SS + (unsigned)(qt0 + 16 * w + l15)) * SS +
         (unsigned)(hi4 * 4);
  }

  const size_t tbase = (size_t)(bh * NKT) * TILE_BYTES + 2048 * w + 16 * l;
  const char* khi_p = ws + WS_KHI + tbase;
  const char* klo_p = ws + WS_KLO + tbase;
  const char* vt_p  = ws + WS_VT  + tbase;

  #pragma unroll 1
  for (int kt = 0; kt < NKT; ++kt,
       khi_p += TILE_BYTES, klo_p += TILE_BYTES, vt_p += TILE_BYTES) {
    __syncthreads();  // prev iter done reading KsHi/KsLo/VtL

    GLOAD16(khi_p,        &KsHi[1024 * w]);
    GLOAD16(khi_p + 1024, &KsHi[1024 * w + 512]);
    GLOAD16(klo_p,        &KsLo[1024 * w]);
    GLOAD16(klo_p + 1024, &KsLo[1024 * w + 512]);
    GLOAD16(vt_p,         &VtL[1024 * w]);
    GLOAD16(vt_p + 1024,  &VtL[1024 * w + 512]);
    __syncthreads();  // drains vmcnt + barrier

    // ---- swapped QK^T: s4[k4][i] = S[k=kt*64+k4*16+hi4*4+i][q=l15-row] ----
    f32x4 s4[4];
    #pragma unroll
    for (int k4 = 0; k4 < 4; ++k4) {
      f32x4 a = (f32x4){0.f, 0.f, 0.f, 0.f};
      #pragma unroll
      for (int c = 0; c < 2; ++c) {
        const int co = ((((c << 2) + hi4) ^ e8) << 3);
        bf16x8 kh = *(const bf16x8*)&KsHi[(k4 * 16 + l15) * 64 + co];
        bf16x8 kl = *(const bf16x8*)&KsLo[(k4 * 16 + l15) * 64 + co];
        a = __builtin_amdgcn_mfma_f32_16x16x32_bf16(kh, qh[c], a, 0, 0, 0);
        a = __builtin_amdgcn_mfma_f32_16x16x32_bf16(kh, ql[c], a, 0, 0, 0);
        a = __builtin_amdgcn_mfma_f32_16x16x32_bf16(kl, qh[c], a, 0, 0, 0);
      }
      s4[k4] = a;
    }

    // ---- mask bits ----
    unsigned msk;
    unsigned bts[16];
    if constexpr (WSMASK) {
      msk = mp[kt * 256];
    } else {
      const unsigned ib = fb + (unsigned)(kt * KT);
      #pragma unroll
      for (int k4 = 0; k4 < 4; ++k4)
        #pragma unroll
        for (int r = 0; r < 4; ++r)
          bts[k4 * 4 + r] = tf_bits(ib + (unsigned)(k4 * 16 + r));
    }

    // ---- in-register online softmax, exp2 domain (one q-row per lane) ----
    float mx01 = fmaxf(fmaxf(s4[0][0], s4[0][1]), fmaxf(s4[0][2], s4[0][3]));
    float mx23 = fmaxf(fmaxf(s4[1][0], s4[1][1]), fmaxf(s4[1][2], s4[1][3]));
    float mx45 = fmaxf(fmaxf(s4[2][0], s4[2][1]), fmaxf(s4[2][2], s4[2][3]));
    float mx67 = fmaxf(fmaxf(s4[3][0], s4[3][1]), fmaxf(s4[3][2], s4[3][3]));
    float mx = fmaxf(fmaxf(mx01, mx23), fmaxf(mx45, mx67));
    mx = fmaxf(mx, __shfl_xor(mx, 16, 64));
    mx = fmaxf(mx, __shfl_xor(mx, 32, 64));
    const float mn = fmaxf(mrow, mx);
    const bool grew = !__all(mn == mrow);
    const float rr = __builtin_amdgcn_exp2f(mrow - mn);
    #pragma unroll
    for (int k4 = 0; k4 < 4; ++k4) {
      s4[k4][0] = __builtin_amdgcn_exp2f(s4[k4][0] - mn);
      s4[k4][1] = __builtin_amdgcn_exp2f(s4[k4][1] - mn);
      s4[k4][2] = __builtin_amdgcn_exp2f(s4[k4][2] - mn);
      s4[k4][3] = __builtin_amdgcn_exp2f(s4[k4][3] - mn);
    }
    float ps0 = (s4[0][0] + s4[0][1]) + (s4[0][2] + s4[0][3]);
    float ps1 = (s4[1][0] + s4[1][1]) + (s4[1][2] + s4[1][3]);
    float ps2 = (s4[2][0] + s4[2][1]) + (s4[2][2] + s4[2][3]);
    float ps3 = (s4[3][0] + s4[3][1]) + (s4[3][2] + s4[3][3]);
    float ps = (ps0 + ps1) + (ps2 + ps3);
    ps += __shfl_xor(ps, 16, 64);
    ps += __shfl_xor(ps, 32, 64);
    lrow = lrow * rr + ps;   // denominator: un-dropped sum
    mrow = mn;

    // ---- dropout-select + pack (cvt_pkrtz) + store P (ds_write_b64) ----
    #pragma unroll
    for (int k4 = 0; k4 < 4; ++k4) {
      float pv[4];
      #pragma unroll
      for (int r = 0; r < 4; ++r) {
        bool keep;
        if constexpr (WSMASK) keep = (msk & (1u << (k4 * 4 + r))) != 0u;
        else                  keep = bts[k4 * 4 + r] < 0xE6666600u;
        pv[r] = keep ? s4[k4][r] : 0.f;
      }
      fp16x2 c01 = __builtin_amdgcn_cvt_pkrtz(pv[0], pv[1]);
      fp16x2 c23 = __builtin_amdgcn_cvt_pkrtz(pv[2], pv[3]);
      uint2 u2;
      u2.x = __builtin_bit_cast(unsigned, c01);
      u2.y = __builtin_bit_cast(unsigned, c23);
      *(uint2*)&Ps[16 * w + l15][k4 * 16 + hi4 * 4] = u2;
    }
    // same-wave RAW on Ps -> compiler lgkmcnt, no barrier

    // ---- PV via MFMA: P(fp16) x V(fp16), fp32 accumulate ----
    half8 pa[2];
    #pragma unroll
    for (int c = 0; c < 2; ++c)
      pa[c] = *(const half8*)&Ps[16 * w + l15][c * 32 + hi4 * 8];
    if (grew) {
      float rfs[4];
      #pragma unroll
      for (int r = 0; r < 4; ++r) rfs[r] = __shfl(rr, hi4 * 4 + r, 64);
      #pragma unroll
      for (int dt = 0; dt < 4; ++dt)
        #pragma unroll
        for (int i = 0; i < 4; ++i) o[dt][i] *= rfs[i];
    }
    #pragma unroll
    for (int dt = 0; dt < 4; ++dt) {
      f32x4 a = o[dt];
      #pragma unroll
      for (int c = 0; c < 2; ++c) {
        const int co = ((((c << 2) + hi4) ^ e8) << 3);
        half8 vh = *(const half8*)&VtL[(dt * 16 + l15) * 64 + co];
        a = __builtin_amdgcn_mfma_f32_16x16x32_f16(pa[c], vh, a, 0, 0, 0);
      }
      o[dt] = a;
    }
  }

  // ---- epilogue ----
  float lr[4];
  #pragma unroll
  for (int r = 0; r < 4; ++r) lr[r] = __shfl(lrow, hi4 * 4 + r, 64);
  #pragma unroll
  for (int r4 = 0; r4 < 4; ++r4) {
    const float inv = 1.0f / (lr[r4] * 0.9f);
    const size_t ob = ((size_t)bh * SS + (qt0 + 16 * w + hi4 * 4 + r4)) * DD + l15;
    #pragma unroll
    for (int dt = 0; dt < 4; ++dt)
      Og[ob + dt * 16] = o[dt][r4] * inv;
  }
}

// ================= fallback (r6 kernel, used if ws too small) =================
__global__ __launch_bounds__(256, 4)
void fused_attn_fallback(const float* __restrict__ Qg, const float* __restrict__ Kg,
                         const float* __restrict__ Vg, float* __restrict__ Og) {
  __shared__ __attribute__((aligned(16))) unsigned short Ks_hi[KT][LP];
  __shared__ __attribute__((aligned(16))) unsigned short Ks_lo[KT][LP];
  __shared__ __attribute__((aligned(16))) _Float16 Vt[DD][LP];
  __shared__ __attribute__((aligned(16))) _Float16 Ps[QT][LP];

  const int t = threadIdx.x, w = t >> 6, l = t & 63, l15 = l & 15, hi4 = l >> 4;
  const int qt0 = blockIdx.x * QT, bh = blockIdx.y, b = bh >> 4, h = bh & 15;
  auto gidx = [&](int s) { return (((size_t)b * SS + s) * HH + h) * DD; };

  bf16x8 qh[2], ql[2];
  {
    const float* qp = Qg + gidx(qt0 + 16 * w + l15) + hi4 * 8;
    #pragma unroll
    for (int c = 0; c < 2; ++c) {
      float f[8];
      *(float4*)&f[0] = *(const float4*)(qp + c * 32);
      *(float4*)&f[4] = *(const float4*)(qp + c * 32 + 4);
      #pragma unroll
      for (int j = 0; j < 8; ++j) {
        float qs = 0.125f * f[j];
        unsigned u = __float_as_uint(qs);
        qh[c][j] = (short)(u >> 16);
        float lo = qs - __uint_as_float(u & 0xFFFF0000u);
        ql[c][j] = (short)(__float_as_uint(lo) >> 16);
      }
    }
  }
  f32x4 o[4];
  #pragma unroll
  for (int i = 0; i < 4; ++i) o[i] = (f32x4){0.f, 0.f, 0.f, 0.f};
  float mrow = -1e30f, lrow = 0.f;
  const unsigned fb =
      ((unsigned)bh * SS + (unsigned)(qt0 + 16 * w + l15)) * SS + (unsigned)(hi4 * 4);
  const int rK = t >> 2, cK = (t & 3) * 16;
  const int rV = t & 63, cV = (t >> 6) * 16;
  const float* kp = Kg + gidx(rK) + cK;
  const float* vp = Vg + gidx(rV) + cV;
  const size_t kstride = (size_t)KT * HH * DD;

  #pragma unroll 1
  for (int kt = 0; kt < SS / KT; ++kt, kp += kstride, vp += kstride) {
    __syncthreads();
    {
      unsigned short khs[16], kls[16];
      #pragma unroll
      for (int u4 = 0; u4 < 4; ++u4) {
        float4 kv = *(const float4*)(kp + u4 * 4);
        float ff[4] = {kv.x, kv.y, kv.z, kv.w};
        #pragma unroll
        for (int j = 0; j < 4; ++j) {
          unsigned u = __float_as_uint(ff[j]);
          khs[u4 * 4 + j] = (unsigned short)(u >> 16);
          float lo = ff[j] - __uint_as_float(u & 0xFFFF0000u);
          kls[u4 * 4 + j] = (unsigned short)(__float_as_uint(lo) >> 16);
        }
      }
      *(bf16x8*)&Ks_hi[rK][cK]     = *(bf16x8*)&khs[0];
      *(bf16x8*)&Ks_hi[rK][cK + 8] = *(bf16x8*)&khs[8];
      *(bf16x8*)&Ks_lo[rK][cK]     = *(bf16x8*)&kls[0];
      *(bf16x8*)&Ks_lo[rK][cK + 8] = *(bf16x8*)&kls[8];
    }
    {
      #pragma unroll
      for (int u4 = 0; u4 < 4; ++u4) {
        float4 vv = *(const float4*)(vp + u4 * 4);
        float ff[4] = {vv.x, vv.y, vv.z, vv.w};
        #pragma unroll
        for (int j = 0; j < 4; ++j)
          Vt[cV + u4 * 4 + j][rV] = (_Float16)ff[j];
      }
    }
    __syncthreads();

    f32x4 s4[4];
    #pragma unroll
    for (int k4 = 0; k4 < 4; ++k4) {
      f32x4 a = (f32x4){0.f, 0.f, 0.f, 0.f};
      #pragma unroll
      for (int c = 0; c < 2; ++c) {
        bf16x8 kh = *(const bf16x8*)&Ks_hi[k4 * 16 + l15][c * 32 + hi4 * 8];
        bf16x8 kl = *(const bf16x8*)&Ks_lo[k4 * 16 + l15][c * 32 + hi4 * 8];
        a = __builtin_amdgcn_mfma_f32_16x16x32_bf16(kh, qh[c], a, 0, 0, 0);
        a = __builtin_amdgcn_mfma_f32_16x16x32_bf16(kh, ql[c], a, 0, 0, 0);
        a = __builtin_amdgcn_mfma_f32_16x16x32_bf16(kl, qh[c], a, 0, 0, 0);
      }
      s4[k4] = a;
    }
    unsigned bts[16];
    {
      const unsigned ib = fb + (unsigned)(kt * KT);
      #pragma unroll
      for (int k4 = 0; k4 < 4; ++k4)
        #pragma unroll
        for (int r = 0; r < 4; ++r)
          bts[k4 * 4 + r] = tf_bits(ib + (unsigned)(k4 * 16 + r));
    }
    float mx01 = fmaxf(fmaxf(s4[0][0], s4[0][1]), fmaxf(s4[0][2], s4[0][3]));
    float mx23 = fmaxf(fmaxf(s4[1][0], s4[1][1]), fmaxf(s4[1][2], s4[1][3]));
    float mx45 = fmaxf(fmaxf(s4[2][0], s4[2][1]), fmaxf(s4[2][2], s4[2][3]));
    float mx67 = fmaxf(fmaxf(s4[3][0], s4[3][1]), fmaxf(s4[3][2], s4[3][3]));
    float mx = fmaxf(fmaxf(mx01, mx23), fmaxf(mx45, mx67));
    mx = fmaxf(mx, __shfl_xor(mx, 16, 64));
    mx = fmaxf(mx, __shfl_xor(mx, 32, 64));
    const float mn = fmaxf(mrow, mx);
    const bool grew = !__all(mn == mrow);
    const float rr = __expf(mrow - mn);
    #pragma unroll
    for (int k4 = 0; k4 < 4; ++k4) {
      s4[k4][0] = __expf(s4[k4][0] - mn);
      s4[k4][1] = __expf(s4[k4][1] - mn);
      s4[k4][2] = __expf(s4[k4][2] - mn);
      s4[k4][3] = __expf(s4[k4][3] - mn);
    }
    float ps0 = (s4[0][0] + s4[0][1]) + (s4[0][2] + s4[0][3]);
    float ps1 = (s4[1][0] + s4[1][1]) + (s4[1][2] + s4[1][3]);
    float ps2 = (s4[2][0] + s4[2][1]) + (s4[2][2] + s4[2][3]);
    float ps3 = (s4[3][0] + s4[3][1]) + (s4[3][2] + s4[3][3]);
    float ps = (ps0 + ps1) + (ps2 + ps3);
    ps += __shfl_xor(ps, 16, 64);
    ps += __shfl_xor(ps, 32, 64);
    lrow = lrow * rr + ps;
    mrow = mn;
    #pragma unroll
    for (int k4 = 0; k4 < 4; ++k4) {
      union { uint2 u2; _Float16 hh[4]; } pk;
      #pragma unroll
      for (int r = 0; r < 4; ++r) {
        float pv = (bts[k4 * 4 + r] < 0xE6666600u) ? s4[k4][r] : 0.f;
        pk.hh[r] = (_Float16)pv;
      }
      *(uint2*)&Ps[16 * w + l15][k4 * 16 + hi4 * 4] = pk.u2;
    }
    __syncthreads();
    half8 pa[2];
    #pragma unroll
    for (int c = 0; c < 2; ++c)
      pa[c] = *(const half8*)&Ps[16 * w + l15][c * 32 + hi4 * 8];
    if (grew) {
      float rfs[4];
      #pragma unroll
      for (int r = 0; r < 4; ++r) rfs[r] = __shfl(rr, hi4 * 4 + r, 64);
      #pragma unroll
      for (int dt = 0; dt < 4; ++dt)
        #pragma unroll
        for (int i = 0; i < 4; ++i) o[dt][i] *= rfs[i];
    }
    #pragma unroll
    for (int dt = 0; dt < 4; ++dt) {
      f32x4 a = o[dt];
      #pragma unroll
      for (int c = 0; c < 2; ++c) {
        half8 vh = *(const half8*)&Vt[dt * 16 + l15][c * 32 + hi4 * 8];
        a = __builtin_amdgcn_mfma_f32_16x16x32_f16(pa[c], vh, a, 0, 0, 0);
      }
      o[dt] = a;
    }
  }
  float lr[4];
  #pragma unroll
  for (int r = 0; r < 4; ++r) lr[r] = __shfl(lrow, hi4 * 4 + r, 64);
  #pragma unroll
  for (int r4 = 0; r4 < 4; ++r4) {
    const float inv = 1.0f / (lr[r4] * 0.9f);
    const size_t ob = ((size_t)bh * SS + (qt0 + 16 * w + hi4 * 4 + r4)) * DD + l15;
    #pragma unroll
    for (int dt = 0; dt < 4; ++dt)
      Og[ob + dt * 16] = o[dt][r4] * inv;
  }
}

extern "C" void kernel_launch(void* const* d_in, const int* in_sizes, int n_in,
                              void* d_out, int out_size, void* d_ws, size_t ws_size,
                              hipStream_t stream) {
  const float* Q = (const float*)d_in[0];
  const float* K = (const float*)d_in[1];
  const float* V = (const float*)d_in[2];
  float* O = (float*)d_out;
  dim3 grid(SS / QT, BB * HH);
  char* wsp = (char*)d_ws;
  if (ws_size >= WS_FULL_NEED) {
    prep_all<<<36864, 256, 0, stream>>>(K, V, wsp);
    fused_attn_t<true><<<grid, dim3(256), 0, stream>>>(
        Q, wsp, (const unsigned short*)(wsp + WS_MASK), O);
  } else if (ws_size >= WS_KV_NEED) {
    prep_all<<<4096, 256, 0, stream>>>(K, V, wsp);
    fused_attn_t<false><<<grid, dim3(256), 0, stream>>>(Q, wsp, nullptr, O);
  } else {
    fused_attn_fallback<<<grid, dim3(256), 0, stream>>>(Q, K, V, O);
  }
}

// Round 11
// 292.273 us; speedup vs baseline: 1.1217x; 1.1217x over previous
//
#include <hip/hip_runtime.h>

#define BB 2
#define HH 16
#define SS 2048
#define DD 64
#define QT 64
#define KT 64
#define NKT (SS / KT)
#define LP 72           // Ps padded row stride (halfs)
#define TILE_BYTES 8192 // one 64x64 fp16/bf16 tile
#define WS_KHI 0
#define WS_KLO (32u * 32u * 8192u)
#define WS_VT  (2u * 32u * 32u * 8192u)
#define WS_KV_NEED ((size_t)3 * 32 * 32 * 8192)
#define QSCALE 0.18033688f  // 0.125 * log2(e): softmax in exp2 domain

using bf16x8 = __attribute__((ext_vector_type(8))) short;
using half8  = __attribute__((ext_vector_type(8))) _Float16;
using f32x4  = __attribute__((ext_vector_type(4))) float;
using fp16x2 = __attribute__((ext_vector_type(2))) __fp16;  // cvt_pkrtz return type

typedef __attribute__((address_space(3))) unsigned lds_u32;
typedef __attribute__((address_space(1))) unsigned gvm_u32;
#define GLOAD16(gp, lp) \
  __builtin_amdgcn_global_load_lds((gvm_u32*)(gp), (lds_u32*)(lp), 16, 0, 0)

// JAX threefry2x32, key (0,42), partitionable: input (0, i), bits = out0^out1.
// keep ⟺ bits < 0xE6666600 (exact reformulation of u<0.9f). Verified r2-r10.
// ~73 VALU inst/cipher x 1.34e8 ciphers is the kernel-suite floor (~250 µs).
__device__ __forceinline__ unsigned tf_bits(unsigned i) {
  const unsigned ks1 = 42u;
  const unsigned ks2 = 0x1BD11BDAu ^ 42u;
  unsigned x0 = 0u;
  unsigned x1 = i + ks1;
#define TF_R(r) { x0 += x1; x1 = __builtin_rotateleft32(x1, r) ^ x0; }
  TF_R(13) TF_R(15) TF_R(26) TF_R(6)
  x0 += ks1; x1 += ks2 + 1u;
  TF_R(17) TF_R(29) TF_R(16) TF_R(24)
  x0 += ks2; x1 += 2u;
  TF_R(13) TF_R(15) TF_R(26) TF_R(6)
  x1 += ks1 + 3u;
  TF_R(17) TF_R(29) TF_R(16) TF_R(24)
  x0 += ks1; x1 += ks2 + 4u;
  TF_R(13) TF_R(15) TF_R(26) TF_R(6)
  x0 += ks2; x1 += 5u;
#undef TF_R
  return x0 ^ x1;
}

// ---- prep: K -> bf16 hi/lo tiles, V -> fp16 transposed tiles, all
// stored with chunk ^= (row&7) swizzle so global_load_lds (linear LDS dest)
// + swizzled ds_read_b128 is bank-conflict-free. Memory-bound, ~25 µs.
__global__ __launch_bounds__(256)
void prep_kv(const float* __restrict__ Kg, const float* __restrict__ Vg,
             char* __restrict__ ws) {
  const int g = blockIdx.x * 256 + threadIdx.x;
  if (blockIdx.x < 2048) {
    // K part: g -> ck(3) | row(6) | kt(5) | bh(5)
    const int ck = g & 7, row = (g >> 3) & 63, kt = (g >> 9) & 31, bh = g >> 14;
    const int b = bh >> 4, h = bh & 15;
    const float* src = Kg + (((size_t)b * SS + kt * 64 + row) * HH + h) * DD + ck * 8;
    float f[8];
    *(float4*)&f[0] = ((const float4*)src)[0];
    *(float4*)&f[4] = ((const float4*)src)[1];
    unsigned short hi[8], lo[8];
    #pragma unroll
    for (int j = 0; j < 8; ++j) {
      unsigned u = __float_as_uint(f[j]);
      hi[j] = (unsigned short)(u >> 16);
      float l = f[j] - __uint_as_float(u & 0xFFFF0000u);
      lo[j] = (unsigned short)(__float_as_uint(l) >> 16);
    }
    const size_t toff = (size_t)(bh * NKT + kt) * TILE_BYTES + row * 128 +
                        ((unsigned)(ck ^ (row & 7))) * 16;
    *(uint4*)(ws + WS_KHI + toff) = *(uint4*)hi;
    *(uint4*)(ws + WS_KLO + toff) = *(uint4*)lo;
  } else {
    // V part: g2 -> d(6) | ck(3) | kt(5) | bh(5); out row = d, chunk over k
    const int g2 = g - (1 << 19);
    const int d = g2 & 63, ck = (g2 >> 6) & 7, kt = (g2 >> 9) & 31, bh = g2 >> 14;
    const int b = bh >> 4, h = bh & 15;
    const float* src = Vg + (((size_t)b * SS + kt * 64 + ck * 8) * HH + h) * DD + d;
    _Float16 hv[8];
    #pragma unroll
    for (int j = 0; j < 8; ++j)
      hv[j] = (_Float16)src[(size_t)j * HH * DD];
    const size_t toff = (size_t)(bh * NKT + kt) * TILE_BYTES + d * 128 +
                        ((unsigned)(ck ^ (d & 7))) * 16;
    *(uint4*)(ws + WS_VT + toff) = *(uint4*)hv;
  }
}

// grid (32, 32): one block per (64-q tile, b*H+h). 4 waves; wave w owns
// q-rows [16w,16w+16). SWAPPED QK^T: mfma(K,Q) -> D[k][q]; lane holds a
// full q-row -> in-register softmax (exp2 domain). Threefry IN-SITU,
// placed in the staging shadow: GLOADs issued, ~2500 cyc of cipher VALU,
// then the barrier's vmcnt drain is free. Single-buffer 33 KB -> 4 blk/CU.
__global__ __launch_bounds__(256, 4)
void fused_attn(const float* __restrict__ Qg, const char* __restrict__ ws,
                float* __restrict__ Og) {
  __shared__ __attribute__((aligned(16))) unsigned short KsHi[4096]; // [64][64]
  __shared__ __attribute__((aligned(16))) unsigned short KsLo[4096];
  __shared__ __attribute__((aligned(16))) _Float16 VtL[4096];        // [d][k]
  __shared__ __attribute__((aligned(16))) _Float16 Ps[QT][LP];

  const int t   = threadIdx.x;
  const int w   = t >> 6;
  const int l   = t & 63;
  const int l15 = l & 15;
  const int hi4 = l >> 4;
  const int e8  = l15 & 7;

  const int qt0 = blockIdx.x * QT;
  const int bh  = blockIdx.y;
  const int b   = bh >> 4, h = bh & 15;

  // ---- Q B-fragments in registers (bf16 hi/lo of QSCALE*q, exp2 domain) ----
  bf16x8 qh[2], ql[2];
  {
    const float* qp = Qg + (((size_t)b * SS + qt0 + 16 * w + l15) * HH + h) * DD + hi4 * 8;
    #pragma unroll
    for (int c = 0; c < 2; ++c) {
      float f[8];
      *(float4*)&f[0] = *(const float4*)(qp + c * 32);
      *(float4*)&f[4] = *(const float4*)(qp + c * 32 + 4);
      #pragma unroll
      for (int j = 0; j < 8; ++j) {
        float qs = QSCALE * f[j];
        unsigned u = __float_as_uint(qs);
        qh[c][j] = (short)(u >> 16);
        float lo = qs - __uint_as_float(u & 0xFFFF0000u);
        ql[c][j] = (short)(__float_as_uint(lo) >> 16);
      }
    }
  }

  f32x4 o[4];
  #pragma unroll
  for (int i = 0; i < 4; ++i) o[i] = (f32x4){0.f, 0.f, 0.f, 0.f};
  float mrow = -1e30f, lrow = 0.f;

  // dropout flat-index base: lane's softmax q-row = qt0+16w+l15, k base hi4*4
  const unsigned fb =
      ((unsigned)bh * SS + (unsigned)(qt0 + 16 * w + l15)) * SS + (unsigned)(hi4 * 4);

  const size_t tbase = (size_t)(bh * NKT) * TILE_BYTES + 2048 * w + 16 * l;
  const char* khi_p = ws + WS_KHI + tbase;
  const char* klo_p = ws + WS_KLO + tbase;
  const char* vt_p  = ws + WS_VT  + tbase;

  #pragma unroll 1
  for (int kt = 0; kt < NKT; ++kt,
       khi_p += TILE_BYTES, klo_p += TILE_BYTES, vt_p += TILE_BYTES) {
    __syncthreads();  // prev iter done reading KsHi/KsLo/VtL

    // ---- stage: 6x global_load_lds (wave w fills segments 2w, 2w+1) ----
    GLOAD16(khi_p,        &KsHi[1024 * w]);
    GLOAD16(khi_p + 1024, &KsHi[1024 * w + 512]);
    GLOAD16(klo_p,        &KsLo[1024 * w]);
    GLOAD16(klo_p + 1024, &KsLo[1024 * w + 512]);
    GLOAD16(vt_p,         &VtL[1024 * w]);
    GLOAD16(vt_p + 1024,  &VtL[1024 * w + 512]);

    // ---- threefry in the staging shadow (~2500 cyc VALU >> load latency) ----
    unsigned bts[16];
    {
      const unsigned ib = fb + (unsigned)(kt * KT);
      #pragma unroll
      for (int k4 = 0; k4 < 4; ++k4)
        #pragma unroll
        for (int r = 0; r < 4; ++r)
          bts[k4 * 4 + r] = tf_bits(ib + (unsigned)(k4 * 16 + r));
    }
    __syncthreads();  // vmcnt mostly drained by cipher work above

    // ---- swapped QK^T: s4[k4][i] = S[k=kt*64+k4*16+hi4*4+i][q=l15-row] ----
    f32x4 s4[4];
    #pragma unroll
    for (int k4 = 0; k4 < 4; ++k4) {
      f32x4 a = (f32x4){0.f, 0.f, 0.f, 0.f};
      #pragma unroll
      for (int c = 0; c < 2; ++c) {
        const int co = ((((c << 2) + hi4) ^ e8) << 3);
        bf16x8 kh = *(const bf16x8*)&KsHi[(k4 * 16 + l15) * 64 + co];
        bf16x8 kl = *(const bf16x8*)&KsLo[(k4 * 16 + l15) * 64 + co];
        a = __builtin_amdgcn_mfma_f32_16x16x32_bf16(kh, qh[c], a, 0, 0, 0);
        a = __builtin_amdgcn_mfma_f32_16x16x32_bf16(kh, ql[c], a, 0, 0, 0);
        a = __builtin_amdgcn_mfma_f32_16x16x32_bf16(kl, qh[c], a, 0, 0, 0);
      }
      s4[k4] = a;
    }

    // ---- in-register online softmax, exp2 domain (one q-row per lane) ----
    float mx01 = fmaxf(fmaxf(s4[0][0], s4[0][1]), fmaxf(s4[0][2], s4[0][3]));
    float mx23 = fmaxf(fmaxf(s4[1][0], s4[1][1]), fmaxf(s4[1][2], s4[1][3]));
    float mx45 = fmaxf(fmaxf(s4[2][0], s4[2][1]), fmaxf(s4[2][2], s4[2][3]));
    float mx67 = fmaxf(fmaxf(s4[3][0], s4[3][1]), fmaxf(s4[3][2], s4[3][3]));
    float mx = fmaxf(fmaxf(mx01, mx23), fmaxf(mx45, mx67));
    mx = fmaxf(mx, __shfl_xor(mx, 16, 64));
    mx = fmaxf(mx, __shfl_xor(mx, 32, 64));
    const float mn = fmaxf(mrow, mx);
    const bool grew = !__all(mn == mrow);
    const float rr = __builtin_amdgcn_exp2f(mrow - mn);
    #pragma unroll
    for (int k4 = 0; k4 < 4; ++k4) {
      s4[k4][0] = __builtin_amdgcn_exp2f(s4[k4][0] - mn);
      s4[k4][1] = __builtin_amdgcn_exp2f(s4[k4][1] - mn);
      s4[k4][2] = __builtin_amdgcn_exp2f(s4[k4][2] - mn);
      s4[k4][3] = __builtin_amdgcn_exp2f(s4[k4][3] - mn);
    }
    float ps0 = (s4[0][0] + s4[0][1]) + (s4[0][2] + s4[0][3]);
    float ps1 = (s4[1][0] + s4[1][1]) + (s4[1][2] + s4[1][3]);
    float ps2 = (s4[2][0] + s4[2][1]) + (s4[2][2] + s4[2][3]);
    float ps3 = (s4[3][0] + s4[3][1]) + (s4[3][2] + s4[3][3]);
    float ps = (ps0 + ps1) + (ps2 + ps3);
    ps += __shfl_xor(ps, 16, 64);
    ps += __shfl_xor(ps, 32, 64);
    lrow = lrow * rr + ps;   // denominator: un-dropped sum
    mrow = mn;

    // ---- dropout-select + pack (cvt_pkrtz) + store P (ds_write_b64) ----
    #pragma unroll
    for (int k4 = 0; k4 < 4; ++k4) {
      float pv[4];
      #pragma unroll
      for (int r = 0; r < 4; ++r)
        pv[r] = (bts[k4 * 4 + r] < 0xE6666600u) ? s4[k4][r] : 0.f;
      fp16x2 c01 = __builtin_amdgcn_cvt_pkrtz(pv[0], pv[1]);
      fp16x2 c23 = __builtin_amdgcn_cvt_pkrtz(pv[2], pv[3]);
      uint2 u2;
      u2.x = __builtin_bit_cast(unsigned, c01);
      u2.y = __builtin_bit_cast(unsigned, c23);
      *(uint2*)&Ps[16 * w + l15][k4 * 16 + hi4 * 4] = u2;
    }
    // same-wave RAW on Ps -> compiler lgkmcnt, no barrier

    // ---- PV via MFMA: P(fp16) x V(fp16), fp32 accumulate ----
    half8 pa[2];
    #pragma unroll
    for (int c = 0; c < 2; ++c)
      pa[c] = *(const half8*)&Ps[16 * w + l15][c * 32 + hi4 * 8];
    if (grew) {
      float rfs[4];
      #pragma unroll
      for (int r = 0; r < 4; ++r) rfs[r] = __shfl(rr, hi4 * 4 + r, 64);
      #pragma unroll
      for (int dt = 0; dt < 4; ++dt)
        #pragma unroll
        for (int i = 0; i < 4; ++i) o[dt][i] *= rfs[i];
    }
    #pragma unroll
    for (int dt = 0; dt < 4; ++dt) {
      f32x4 a = o[dt];
      #pragma unroll
      for (int c = 0; c < 2; ++c) {
        const int co = ((((c << 2) + hi4) ^ e8) << 3);
        half8 vh = *(const half8*)&VtL[(dt * 16 + l15) * 64 + co];
        a = __builtin_amdgcn_mfma_f32_16x16x32_f16(pa[c], vh, a, 0, 0, 0);
      }
      o[dt] = a;
    }
  }

  // ---- epilogue ----
  float lr[4];
  #pragma unroll
  for (int r = 0; r < 4; ++r) lr[r] = __shfl(lrow, hi4 * 4 + r, 64);
  #pragma unroll
  for (int r4 = 0; r4 < 4; ++r4) {
    const float inv = 1.0f / (lr[r4] * 0.9f);
    const size_t ob = ((size_t)bh * SS + (qt0 + 16 * w + hi4 * 4 + r4)) * DD + l15;
    #pragma unroll
    for (int dt = 0; dt < 4; ++dt)
      Og[ob + dt * 16] = o[dt][r4] * inv;
  }
}

// ================= fallback (r6 kernel, used if ws too small) =================
__global__ __launch_bounds__(256, 4)
void fused_attn_fallback(const float* __restrict__ Qg, const float* __restrict__ Kg,
                         const float* __restrict__ Vg, float* __restrict__ Og) {
  __shared__ __attribute__((aligned(16))) unsigned short Ks_hi[KT][LP];
  __shared__ __attribute__((aligned(16))) unsigned short Ks_lo[KT][LP];
  __shared__ __attribute__((aligned(16))) _Float16 Vt[DD][LP];
  __shared__ __attribute__((aligned(16))) _Float16 Ps[QT][LP];

  const int t = threadIdx.x, w = t >> 6, l = t & 63, l15 = l & 15, hi4 = l >> 4;
  const int qt0 = blockIdx.x * QT, bh = blockIdx.y, b = bh >> 4, h = bh & 15;
  auto gidx = [&](int s) { return (((size_t)b * SS + s) * HH + h) * DD; };

  bf16x8 qh[2], ql[2];
  {
    const float* qp = Qg + gidx(qt0 + 16 * w + l15) + hi4 * 8;
    #pragma unroll
    for (int c = 0; c < 2; ++c) {
      float f[8];
      *(float4*)&f[0] = *(const float4*)(qp + c * 32);
      *(float4*)&f[4] = *(const float4*)(qp + c * 32 + 4);
      #pragma unroll
      for (int j = 0; j < 8; ++j) {
        float qs = 0.125f * f[j];
        unsigned u = __float_as_uint(qs);
        qh[c][j] = (short)(u >> 16);
        float lo = qs - __uint_as_float(u & 0xFFFF0000u);
        ql[c][j] = (short)(__float_as_uint(lo) >> 16);
      }
    }
  }
  f32x4 o[4];
  #pragma unroll
  for (int i = 0; i < 4; ++i) o[i] = (f32x4){0.f, 0.f, 0.f, 0.f};
  float mrow = -1e30f, lrow = 0.f;
  const unsigned fb =
      ((unsigned)bh * SS + (unsigned)(qt0 + 16 * w + l15)) * SS + (unsigned)(hi4 * 4);
  const int rK = t >> 2, cK = (t & 3) * 16;
  const int rV = t & 63, cV = (t >> 6) * 16;
  const float* kp = Kg + gidx(rK) + cK;
  const float* vp = Vg + gidx(rV) + cV;
  const size_t kstride = (size_t)KT * HH * DD;

  #pragma unroll 1
  for (int kt = 0; kt < SS / KT; ++kt, kp += kstride, vp += kstride) {
    __syncthreads();
    {
      unsigned short khs[16], kls[16];
      #pragma unroll
      for (int u4 = 0; u4 < 4; ++u4) {
        float4 kv = *(const float4*)(kp + u4 * 4);
        float ff[4] = {kv.x, kv.y, kv.z, kv.w};
        #pragma unroll
        for (int j = 0; j < 4; ++j) {
          unsigned u = __float_as_uint(ff[j]);
          khs[u4 * 4 + j] = (unsigned short)(u >> 16);
          float lo = ff[j] - __uint_as_float(u & 0xFFFF0000u);
          kls[u4 * 4 + j] = (unsigned short)(__float_as_uint(lo) >> 16);
        }
      }
      *(bf16x8*)&Ks_hi[rK][cK]     = *(bf16x8*)&khs[0];
      *(bf16x8*)&Ks_hi[rK][cK + 8] = *(bf16x8*)&khs[8];
      *(bf16x8*)&Ks_lo[rK][cK]     = *(bf16x8*)&kls[0];
      *(bf16x8*)&Ks_lo[rK][cK + 8] = *(bf16x8*)&kls[8];
    }
    {
      #pragma unroll
      for (int u4 = 0; u4 < 4; ++u4) {
        float4 vv = *(const float4*)(vp + u4 * 4);
        float ff[4] = {vv.x, vv.y, vv.z, vv.w};
        #pragma unroll
        for (int j = 0; j < 4; ++j)
          Vt[cV + u4 * 4 + j][rV] = (_Float16)ff[j];
      }
    }
    __syncthreads();

    f32x4 s4[4];
    #pragma unroll
    for (int k4 = 0; k4 < 4; ++k4) {
      f32x4 a = (f32x4){0.f, 0.f, 0.f, 0.f};
      #pragma unroll
      for (int c = 0; c < 2; ++c) {
        bf16x8 kh = *(const bf16x8*)&Ks_hi[k4 * 16 + l15][c * 32 + hi4 * 8];
        bf16x8 kl = *(const bf16x8*)&Ks_lo[k4 * 16 + l15][c * 32 + hi4 * 8];
        a = __builtin_amdgcn_mfma_f32_16x16x32_bf16(kh, qh[c], a, 0, 0, 0);
        a = __builtin_amdgcn_mfma_f32_16x16x32_bf16(kh, ql[c], a, 0, 0, 0);
        a = __builtin_amdgcn_mfma_f32_16x16x32_bf16(kl, qh[c], a, 0, 0, 0);
      }
      s4[k4] = a;
    }
    unsigned bts[16];
    {
      const unsigned ib = fb + (unsigned)(kt * KT);
      #pragma unroll
      for (int k4 = 0; k4 < 4; ++k4)
        #pragma unroll
        for (int r = 0; r < 4; ++r)
          bts[k4 * 4 + r] = tf_bits(ib + (unsigned)(k4 * 16 + r));
    }
    float mx01 = fmaxf(fmaxf(s4[0][0], s4[0][1]), fmaxf(s4[0][2], s4[0][3]));
    float mx23 = fmaxf(fmaxf(s4[1][0], s4[1][1]), fmaxf(s4[1][2], s4[1][3]));
    float mx45 = fmaxf(fmaxf(s4[2][0], s4[2][1]), fmaxf(s4[2][2], s4[2][3]));
    float mx67 = fmaxf(fmaxf(s4[3][0], s4[3][1]), fmaxf(s4[3][2], s4[3][3]));
    float mx = fmaxf(fmaxf(mx01, mx23), fmaxf(mx45, mx67));
    mx = fmaxf(mx, __shfl_xor(mx, 16, 64));
    mx = fmaxf(mx, __shfl_xor(mx, 32, 64));
    const float mn = fmaxf(mrow, mx);
    const bool grew = !__all(mn == mrow);
    const float rr = __expf(mrow - mn);
    #pragma unroll
    for (int k4 = 0; k4 < 4; ++k4) {
      s4[k4][0] = __expf(s4[k4][0] - mn);
      s4[k4][1] = __expf(s4[k4][1] - mn);
      s4[k4][2] = __expf(s4[k4][2] - mn);
      s4[k4][3] = __expf(s4[k4][3] - mn);
    }
    float ps0 = (s4[0][0] + s4[0][1]) + (s4[0][2] + s4[0][3]);
    float ps1 = (s4[1][0] + s4[1][1]) + (s4[1][2] + s4[1][3]);
    float ps2 = (s4[2][0] + s4[2][1]) + (s4[2][2] + s4[2][3]);
    float ps3 = (s4[3][0] + s4[3][1]) + (s4[3][2] + s4[3][3]);
    float ps = (ps0 + ps1) + (ps2 + ps3);
    ps += __shfl_xor(ps, 16, 64);
    ps += __shfl_xor(ps, 32, 64);
    lrow = lrow * rr + ps;
    mrow = mn;
    #pragma unroll
    for (int k4 = 0; k4 < 4; ++k4) {
      union { uint2 u2; _Float16 hh[4]; } pk;
      #pragma unroll
      for (int r = 0; r < 4; ++r) {
        float pv = (bts[k4 * 4 + r] < 0xE6666600u) ? s4[k4][r] : 0.f;
        pk.hh[r] = (_Float16)pv;
      }
      *(uint2*)&Ps[16 * w + l15][k4 * 16 + hi4 * 4] = pk.u2;
    }
    __syncthreads();
    half8 pa[2];
    #pragma unroll
    for (int c = 0; c < 2; ++c)
      pa[c] = *(const half8*)&Ps[16 * w + l15][c * 32 + hi4 * 8];
    if (grew) {
      float rfs[4];
      #pragma unroll
      for (int r = 0; r < 4; ++r) rfs[r] = __shfl(rr, hi4 * 4 + r, 64);
      #pragma unroll
      for (int dt = 0; dt < 4; ++dt)
        #pragma unroll
        for (int i = 0; i < 4; ++i) o[dt][i] *= rfs[i];
    }
    #pragma unroll
    for (int dt = 0; dt < 4; ++dt) {
      f32x4 a = o[dt];
      #pragma unroll
      for (int c = 0; c < 2; ++c) {
        half8 vh = *(const half8*)&Vt[dt * 16 + l15][c * 32 + hi4 * 8];
        a = __builtin_amdgcn_mfma_f32_16x16x32_f16(pa[c], vh, a, 0, 0, 0);
      }
      o[dt] = a;
    }
  }
  float lr[4];
  #pragma unroll
  for (int r = 0; r < 4; ++r) lr[r] = __shfl(lrow, hi4 * 4 + r, 64);
  #pragma unroll
  for (int r4 = 0; r4 < 4; ++r4) {
    const float inv = 1.0f / (lr[r4] * 0.9f);
    const size_t ob = ((size_t)bh * SS + (qt0 + 16 * w + hi4 * 4 + r4)) * DD + l15;
    #pragma unroll
    for (int dt = 0; dt < 4; ++dt)
      Og[ob + dt * 16] = o[dt][r4] * inv;
  }
}

extern "C" void kernel_launch(void* const* d_in, const int* in_sizes, int n_in,
                              void* d_out, int out_size, void* d_ws, size_t ws_size,
                              hipStream_t stream) {
  const float* Q = (const float*)d_in[0];
  const float* K = (const float*)d_in[1];
  const float* V = (const float*)d_in[2];
  float* O = (float*)d_out;
  dim3 grid(SS / QT, BB * HH);
  char* wsp = (char*)d_ws;
  if (ws_size >= WS_KV_NEED) {
    prep_kv<<<4096, 256, 0, stream>>>(K, V, wsp);
    fused_attn<<<grid, dim3(256), 0, stream>>>(Q, wsp, O);
  } else {
    fused_attn_fallback<<<grid, dim3(256), 0, stream>>>(Q, K, V, O);
  }
}